// Round 5
// baseline (3011.525 us; speedup 1.0000x reference)
//
#include <hip/hip_runtime.h>

// ============================================================================
// Fused 3-stage LSTM (centerline H=32 T=100, encoder H=64 T=20, decoder H=96
// T=30 + 96->2 projection), B=131072 independent samples.
// Round 5: barrier-free wave-autonomous cent/enc (each wave owns 16 samples;
// h round-trips through a private LDS region, exploiting in-order per-wave LDS
// execution -> NO __syncthreads for 120 of 150 steps). Decoder cooperative
// (12 waves, TB=192) with ONE raw lgkmcnt-barrier/step, ALL weights streamed
// from L2 in-loop (r3-proven no-spill). h/c stored packed (hi<<16|lo) u32;
// A-fragments rebuilt with v_perm_b32. x-term computed in exact fp32 VALU.
// c carried in registers cent/enc; packed LDS stash only at the dec boundary.
// ============================================================================

#define B_TOTAL 131072
#define TB 192
#define NBLK 683                         // ceil(131072/192)
#define SL 100                           // LDS row stride in dwords

typedef __attribute__((ext_vector_type(8))) short bf16x8;
typedef __attribute__((ext_vector_type(4))) float f32x4;
typedef __attribute__((ext_vector_type(4))) unsigned int u32x4;

#define MFMA16(a, b, c) __builtin_amdgcn_mfma_f32_16x16x32_bf16((a), (b), (c), 0, 0, 0)
#define PERM(a, b, s) __builtin_amdgcn_perm((a), (b), (s))

#ifndef __has_builtin
#define __has_builtin(x) 0
#endif
#if __has_builtin(__builtin_amdgcn_exp2f)
#define EXP2(x) __builtin_amdgcn_exp2f(x)
#else
#define EXP2(x) exp2f(x)
#endif
#if __has_builtin(__builtin_amdgcn_rcpf)
#define RCPF(x) __builtin_amdgcn_rcpf(x)
#else
#define RCPF(x) (1.0f / (x))
#endif

#define L2E 1.44269504088896340736f
#define NEG2L2E (-2.88539008177792681472f)

// ws layout (offsets in ushorts). Weights prescaled (i,f,o rows by log2e,
// g rows by 2*log2e), decoder Wih+Whh combined, x-columns appended, hi/lo split.
#define OFF_WD_HI 0         // [384][96]
#define OFF_WD_LO 36864
#define OFF_WE_HI 73728     // [256][96]  (cols 0..63 = Whh, 64..65 = Wih, rest 0)
#define OFF_WE_LO 98304
#define OFF_WC_HI 122880    // [128][64]  (cols 0..31 = Whh, 32..33 = Wih, rest 0)
#define OFF_WC_LO 131072
#define OFF_WM_HI 139264    // [16][96]   (rows 0..1 = W_emb, rest 0)
#define OFF_WM_LO 140800
#define OFF_BIAS  142336    // floats: bd[384], be[256], bc[128], bemb[2]

// Raw step barrier for the decoder: wait LDS only; global loads stay in flight.
#define STEP_BARRIER() asm volatile("s_waitcnt lgkmcnt(0)\n\ts_barrier" ::: "memory")

__device__ __forceinline__ void split2(float f, unsigned short& hi, unsigned short& lo)
{
  unsigned int u = __float_as_uint(f);
  hi = (unsigned short)(u >> 16);
  float r = f - __uint_as_float(u & 0xFFFF0000u);   // exact residual
  lo = (unsigned short)(__float_as_uint(r) >> 16);
}

__device__ __forceinline__ unsigned int packhl(float f)
{
  unsigned int u = __float_as_uint(f);
  unsigned int hb = u & 0xFFFF0000u;
  float r = f - __uint_as_float(hb);
  return hb | (__float_as_uint(r) >> 16);
}

__device__ __forceinline__ float b2f(unsigned int hi16, unsigned int lo16)
{
  return __uint_as_float(hi16 << 16) + __uint_as_float(lo16 << 16);
}

__device__ __forceinline__ f32x4 splat4(float v)
{
  f32x4 a; a[0] = v; a[1] = v; a[2] = v; a[3] = v; return a;
}

// 8 packed u32 (cols k..k+7) -> hi/lo bf16x8 A-fragments.
__device__ __forceinline__ void extract8(u32x4 p0, u32x4 p1, bf16x8& hi, bf16x8& lo)
{
  u32x4 h, l;
  h[0] = PERM(p0[1], p0[0], 0x07060302u); h[1] = PERM(p0[3], p0[2], 0x07060302u);
  h[2] = PERM(p1[1], p1[0], 0x07060302u); h[3] = PERM(p1[3], p1[2], 0x07060302u);
  l[0] = PERM(p0[1], p0[0], 0x05040100u); l[1] = PERM(p0[3], p0[2], 0x05040100u);
  l[2] = PERM(p1[1], p1[0], 0x05040100u); l[3] = PERM(p1[3], p1[2], 0x05040100u);
  hi = __builtin_bit_cast(bf16x8, h);
  lo = __builtin_bit_cast(bf16x8, l);
}

// LSTM unit update: gates (prescaled by log2e / 2log2e) -> new c (fp32 reg),
// returns packed bf16 hi/lo of h.
__device__ __forceinline__ unsigned int lstm_unit(float ig, float fg, float gg, float og, float& c)
{
  float si = RCPF(1.0f + EXP2(-ig));
  float sf = RCPF(1.0f + EXP2(-fg));
  float so = RCPF(1.0f + EXP2(-og));
  float tg = 2.0f * RCPF(1.0f + EXP2(-gg)) - 1.0f;
  float cn = sf * c + si * tg;
  c = cn;
  float tc = 2.0f * RCPF(1.0f + EXP2(cn * NEG2L2E)) - 1.0f;
  return packhl(so * tc);
}

// ---------------------------------------------------------------------------
// Prep kernel: combine/prescale/split weights into ws.
// ---------------------------------------------------------------------------
__global__ void prep_weights(
    const float* __restrict__ Wih_c, const float* __restrict__ Whh_c,
    const float* __restrict__ bih_c, const float* __restrict__ bhh_c,
    const float* __restrict__ Wih_e, const float* __restrict__ Whh_e,
    const float* __restrict__ bih_e, const float* __restrict__ bhh_e,
    const float* __restrict__ Wih_d, const float* __restrict__ Whh_d,
    const float* __restrict__ bih_d, const float* __restrict__ bhh_d,
    const float* __restrict__ W_emb, const float* __restrict__ b_emb,
    unsigned short* __restrict__ wsu)
{
  int idx = blockIdx.x * 256 + threadIdx.x;
  float* wsf = (float*)(wsu + OFF_BIAS);
  unsigned short h, l;
  if (idx < 384 * 96) {
    int j = idx / 96;
    float s = (j >= 192 && j < 288) ? 2.0f * L2E : L2E;
    float w = (Wih_d[idx] + Whh_d[idx]) * s;
    split2(w, h, l);
    wsu[OFF_WD_HI + idx] = h; wsu[OFF_WD_LO + idx] = l;
  }
  if (idx < 256 * 96) {
    int j = idx / 96, k = idx - j * 96;
    float s = (j >= 128 && j < 192) ? 2.0f * L2E : L2E;
    float w = 0.0f;
    if (k < 64) w = Whh_e[j * 64 + k] * s;
    else if (k < 66) w = Wih_e[j * 2 + (k - 64)] * s;
    split2(w, h, l);
    wsu[OFF_WE_HI + idx] = h; wsu[OFF_WE_LO + idx] = l;
  }
  if (idx < 128 * 64) {
    int j = idx / 64, k = idx - j * 64;
    float s = (j >= 64 && j < 96) ? 2.0f * L2E : L2E;
    float w = 0.0f;
    if (k < 32) w = Whh_c[j * 32 + k] * s;
    else if (k < 34) w = Wih_c[j * 2 + (k - 32)] * s;
    split2(w, h, l);
    wsu[OFF_WC_HI + idx] = h; wsu[OFF_WC_LO + idx] = l;
  }
  if (idx < 16 * 96) {
    int n = idx / 96, k = idx - n * 96;
    float w = (n < 2) ? W_emb[n * 96 + k] : 0.0f;
    split2(w, h, l);
    wsu[OFF_WM_HI + idx] = h; wsu[OFF_WM_LO + idx] = l;
  }
  if (idx < 384) {
    float s = (idx >= 192 && idx < 288) ? 2.0f * L2E : L2E;
    wsf[idx] = (bih_d[idx] + bhh_d[idx]) * s;
  }
  if (idx < 256) {
    float s = (idx >= 128 && idx < 192) ? 2.0f * L2E : L2E;
    wsf[384 + idx] = (bih_e[idx] + bhh_e[idx]) * s;
  }
  if (idx < 128) {
    float s = (idx >= 64 && idx < 96) ? 2.0f * L2E : L2E;
    wsf[640 + idx] = (bih_c[idx] + bhh_c[idx]) * s;
  }
  if (idx < 2) wsf[768 + idx] = b_emb[idx];
}

// ---------------------------------------------------------------------------
// Main fused kernel. Block = 768 threads (12 waves), TB = 192 samples.
// LDS: shl[2][192][100] packed-u32 h (and c-stash in buf1 at the dec boundary).
// ---------------------------------------------------------------------------
__global__ __launch_bounds__(768, 3) void lstm_fused(
    const float* __restrict__ traj,
    const float* __restrict__ ctr,
    const unsigned short* __restrict__ wsu,
    float* __restrict__ out)
{
  const int tid = threadIdx.x;
  const int wid = tid >> 6;
  const int lane = tid & 63;
  const int lr = lane & 15;
  const int lg = lane >> 4;
  const int blk = blockIdx.x;

  const float* bias_d = (const float*)(wsu + OFF_BIAS);
  const float* bias_e = bias_d + 384;
  const float* bias_c = bias_d + 640;
  const float* bias_m = bias_d + 768;

  __shared__ unsigned int shl[2][TB * SL];   // 153,600 B

  unsigned int* my = &shl[0][(wid * 16) * SL];   // this wave's 16 rows (buf0)
  const int rowA = lr * SL;                       // A-frag read row base
  const long sbase = (long)blk * TB + wid * 16;   // first sample of this wave

  // Zero own rows of buf0 (h0 = 0). Own-wave LDS: no barrier needed.
  for (int i = lane; i < 16 * SL; i += 64) my[i] = 0u;

  // ================= centerline LSTM: H=32, T=100 (cols 64..95) ============
  {
    bf16x8 Bh[2][4], Bl[2][4];
    float2 wx[2][4];
    float bias[2][4], cc[2][4];
#pragma unroll
    for (int ut = 0; ut < 2; ++ut)
#pragma unroll
      for (int g = 0; g < 4; ++g) {
        int j = g * 32 + ut * 16 + lr;
        Bh[ut][g] = *(const bf16x8*)(wsu + OFF_WC_HI + j * 64 + lg * 8);
        Bl[ut][g] = *(const bf16x8*)(wsu + OFF_WC_LO + j * 64 + lg * 8);
        wx[ut][g].x = b2f(wsu[OFF_WC_HI + j * 64 + 32], wsu[OFF_WC_LO + j * 64 + 32]);
        wx[ut][g].y = b2f(wsu[OFF_WC_HI + j * 64 + 33], wsu[OFF_WC_LO + j * 64 + 33]);
        bias[ut][g] = bias_c[j];
        cc[ut][g] = 0.0f;   // reuse [ut][q] slots; q==g count
      }
    const float* xp[4];
#pragma unroll
    for (int q = 0; q < 4; ++q) {
      long s = sbase + lg * 4 + q;
      if (s > B_TOTAL - 1) s = B_TOTAL - 1;
      xp[q] = ctr + s * 200;
    }
    float2 xc[4];
#pragma unroll
    for (int q = 0; q < 4; ++q) xc[q] = *(const float2*)(xp[q]);

    for (int t = 0; t < 100; ++t) {
      int tn = t < 99 ? t + 1 : 99;
      float2 xn[4];
#pragma unroll
      for (int q = 0; q < 4; ++q) xn[q] = *(const float2*)(xp[q] + 2 * tn);
      // A-fragments: own rows, cols 64..95 (in place)
      u32x4 p0 = *(const u32x4*)&my[rowA + 64 + lg * 8];
      u32x4 p1 = *(const u32x4*)&my[rowA + 64 + lg * 8 + 4];
      bf16x8 Ahi, Alo;
      extract8(p0, p1, Ahi, Alo);
#pragma unroll
      for (int ut = 0; ut < 2; ++ut) {
        f32x4 acc[4];
#pragma unroll
        for (int g = 0; g < 4; ++g) {
          f32x4 a = splat4(bias[ut][g]);
#pragma unroll
          for (int q = 0; q < 4; ++q)
            a[q] += xc[q].x * wx[ut][g].x + xc[q].y * wx[ut][g].y;
          a = MFMA16(Ahi, Bh[ut][g], a);
          a = MFMA16(Alo, Bh[ut][g], a);
          a = MFMA16(Ahi, Bl[ut][g], a);
          acc[g] = a;
        }
#pragma unroll
        for (int q = 0; q < 4; ++q) {
          unsigned int hn = lstm_unit(acc[0][q], acc[1][q], acc[2][q], acc[3][q], cc[ut][q]);
          my[(lg * 4 + q) * SL + 64 + ut * 16 + lr] = hn;
        }
      }
#pragma unroll
      for (int q = 0; q < 4; ++q) xc[q] = xn[q];
    }
    // Stash cent c (packed) into buf1 cols 64..95 for the decoder.
#pragma unroll
    for (int ut = 0; ut < 2; ++ut)
#pragma unroll
      for (int q = 0; q < 4; ++q)
        shl[1][(wid * 16 + lg * 4 + q) * SL + 64 + ut * 16 + lr] = packhl(cc[ut][q]);
  }

  // ================= encoder LSTM: H=64, T=20 (cols 0..63) =================
  {
    float2 wx[4][4];
    float bias[4][4], cc[4][4];
#pragma unroll
    for (int ut = 0; ut < 4; ++ut)
#pragma unroll
      for (int g = 0; g < 4; ++g) {
        int j = g * 64 + ut * 16 + lr;
        wx[ut][g].x = b2f(wsu[OFF_WE_HI + j * 96 + 64], wsu[OFF_WE_LO + j * 96 + 64]);
        wx[ut][g].y = b2f(wsu[OFF_WE_HI + j * 96 + 65], wsu[OFF_WE_LO + j * 96 + 65]);
        bias[ut][g] = bias_e[j];
        cc[ut][g] = 0.0f;
      }
    const float* xp[4];
#pragma unroll
    for (int q = 0; q < 4; ++q) {
      long s = sbase + lg * 4 + q;
      if (s > B_TOTAL - 1) s = B_TOTAL - 1;
      xp[q] = traj + s * 40;
    }
    float2 xc[4];
#pragma unroll
    for (int q = 0; q < 4; ++q) xc[q] = *(const float2*)(xp[q]);

    for (int t = 0; t < 20; ++t) {
      int tn = t < 19 ? t + 1 : 19;
      float2 xn[4];
#pragma unroll
      for (int q = 0; q < 4; ++q) xn[q] = *(const float2*)(xp[q] + 2 * tn);
      int tofs = 0;
      asm volatile("" : "+v"(tofs));   // keep streamed B loads in-loop
      bf16x8 Ahi[2], Alo[2];
#pragma unroll
      for (int kb = 0; kb < 2; ++kb) {
        u32x4 p0 = *(const u32x4*)&my[rowA + kb * 32 + lg * 8];
        u32x4 p1 = *(const u32x4*)&my[rowA + kb * 32 + lg * 8 + 4];
        extract8(p0, p1, Ahi[kb], Alo[kb]);
      }
#pragma unroll
      for (int ut = 0; ut < 4; ++ut) {
        f32x4 acc[4];
#pragma unroll
        for (int g = 0; g < 4; ++g) {
          f32x4 a = splat4(bias[ut][g]);
#pragma unroll
          for (int q = 0; q < 4; ++q)
            a[q] += xc[q].x * wx[ut][g].x + xc[q].y * wx[ut][g].y;
          acc[g] = a;
        }
#pragma unroll
        for (int kb = 0; kb < 2; ++kb)
#pragma unroll
          for (int g = 0; g < 4; ++g) {
            int bo = (g * 64 + ut * 16 + lr) * 96 + kb * 32 + lg * 8 + tofs;
            bf16x8 bhi = *(const bf16x8*)(wsu + OFF_WE_HI + bo);
            bf16x8 blo = *(const bf16x8*)(wsu + OFF_WE_LO + bo);
            acc[g] = MFMA16(Ahi[kb], bhi, acc[g]);
            acc[g] = MFMA16(Alo[kb], bhi, acc[g]);
            acc[g] = MFMA16(Ahi[kb], blo, acc[g]);
          }
#pragma unroll
        for (int q = 0; q < 4; ++q) {
          unsigned int hn = lstm_unit(acc[0][q], acc[1][q], acc[2][q], acc[3][q], cc[ut][q]);
          my[(lg * 4 + q) * SL + ut * 16 + lr] = hn;
        }
      }
#pragma unroll
      for (int q = 0; q < 4; ++q) xc[q] = xn[q];
    }
    // Stash enc c (packed) into buf1 cols 0..63.
#pragma unroll
    for (int ut = 0; ut < 4; ++ut)
#pragma unroll
      for (int q = 0; q < 4; ++q)
        shl[1][(wid * 16 + lg * 4 + q) * SL + ut * 16 + lr] = packhl(cc[ut][q]);
  }

  __syncthreads();   // buf0 = h0 (all 96 cols), buf1 = c0 stash: dec may start

  // ================= decoder LSTM: H=96, T=30 + projection =================
  {
    const int ut = wid % 6;
    const int rh = wid / 6;                // rt = rh + 2k, k = 0..5
    const int ucol = ut * 16 + lr;
    float bias[4];
#pragma unroll
    for (int g = 0; g < 4; ++g) bias[g] = bias_d[g * 96 + ucol];
    float pbias = (lr < 2) ? bias_m[lr] : 0.0f;
    float cc[6][4];
#pragma unroll
    for (int k = 0; k < 6; ++k)
#pragma unroll
      for (int q = 0; q < 4; ++q) {
        int row = (rh + 2 * k) * 16 + lg * 4 + q;
        unsigned int p = shl[1][row * SL + ucol];
        cc[k][q] = b2f(p >> 16, p & 0xFFFFu);
      }

    for (int t = 0; t < 30; ++t) {
      const unsigned int* rb = shl[t & 1];
      unsigned int* wb = shl[(t & 1) ^ 1];
      int tofs = 0;
      asm volatile("" : "+v"(tofs));   // keep streamed B loads in-loop
#pragma unroll
      for (int half = 0; half < 2; ++half) {
        f32x4 acc[3][4];
#pragma unroll
        for (int k = 0; k < 3; ++k)
#pragma unroll
          for (int g = 0; g < 4; ++g) acc[k][g] = splat4(bias[g]);
#pragma unroll
        for (int kb = 0; kb < 3; ++kb) {
          bf16x8 Ahi[3], Alo[3];
#pragma unroll
          for (int k = 0; k < 3; ++k) {
            int rt = rh + 2 * (half * 3 + k);
            int rbase = (rt * 16 + lr) * SL + kb * 32 + lg * 8;
            u32x4 p0 = *(const u32x4*)&rb[rbase];
            u32x4 p1 = *(const u32x4*)&rb[rbase + 4];
            extract8(p0, p1, Ahi[k], Alo[k]);
          }
#pragma unroll
          for (int g = 0; g < 4; ++g) {
            int bo = (g * 96 + ucol) * 96 + kb * 32 + lg * 8 + tofs;
            bf16x8 bhi = *(const bf16x8*)(wsu + OFF_WD_HI + bo);
            bf16x8 blo = *(const bf16x8*)(wsu + OFF_WD_LO + bo);
#pragma unroll
            for (int k = 0; k < 3; ++k) {
              acc[k][g] = MFMA16(Ahi[k], bhi, acc[k][g]);
              acc[k][g] = MFMA16(Alo[k], bhi, acc[k][g]);
              acc[k][g] = MFMA16(Ahi[k], blo, acc[k][g]);
            }
          }
        }
#pragma unroll
        for (int k = 0; k < 3; ++k)
#pragma unroll
          for (int q = 0; q < 4; ++q) {
            unsigned int hn = lstm_unit(acc[k][0][q], acc[k][1][q], acc[k][2][q],
                                        acc[k][3][q], cc[half * 3 + k][q]);
            int rt = rh + 2 * (half * 3 + k);
            wb[(rt * 16 + lg * 4 + q) * SL + ucol] = hn;
          }
      }
      STEP_BARRIER();   // h(t+1) complete in wb

      // projection: wave w handles row-tile rt = wid
      {
        f32x4 ap = splat4(pbias);
        int rbase = (wid * 16 + lr) * SL;
#pragma unroll
        for (int kb = 0; kb < 3; ++kb) {
          u32x4 p0 = *(const u32x4*)&wb[rbase + kb * 32 + lg * 8];
          u32x4 p1 = *(const u32x4*)&wb[rbase + kb * 32 + lg * 8 + 4];
          bf16x8 phh, pll;
          extract8(p0, p1, phh, pll);
          int mo = lr * 96 + kb * 32 + lg * 8 + tofs;
          bf16x8 bmh = *(const bf16x8*)(wsu + OFF_WM_HI + mo);
          bf16x8 bml = *(const bf16x8*)(wsu + OFF_WM_LO + mo);
          ap = MFMA16(phh, bmh, ap);
          ap = MFMA16(pll, bmh, ap);
          ap = MFMA16(phh, bml, ap);
        }
        if (lr < 2) {
#pragma unroll
          for (int q = 0; q < 4; ++q) {
            long s = (long)blk * TB + wid * 16 + lg * 4 + q;
            if (s < B_TOTAL) out[s * 60 + t * 2 + lr] = ap[q];
          }
        }
      }
    }
  }
}

extern "C" void kernel_launch(void* const* d_in, const int* in_sizes, int n_in,
                              void* d_out, int out_size, void* d_ws, size_t ws_size,
                              hipStream_t stream)
{
  if (ws_size < 287752) return;   // need ~288 KB of scratch for prepped weights
  const float* traj = (const float*)d_in[0];
  const float* ctr  = (const float*)d_in[1];
  prep_weights<<<144, 256, 0, stream>>>(
      (const float*)d_in[2],  (const float*)d_in[3],  (const float*)d_in[4],  (const float*)d_in[5],
      (const float*)d_in[6],  (const float*)d_in[7],  (const float*)d_in[8],  (const float*)d_in[9],
      (const float*)d_in[10], (const float*)d_in[11], (const float*)d_in[12], (const float*)d_in[13],
      (const float*)d_in[14], (const float*)d_in[15],
      (unsigned short*)d_ws);
  lstm_fused<<<NBLK, 768, 0, stream>>>(traj, ctr, (const unsigned short*)d_ws, (float*)d_out);
}